// Round 1
// baseline (5362.955 us; speedup 1.0000x reference)
//
#include <hip/hip_runtime.h>

// Forward warp (bilinear splat): im0 [B,C,H,W] f32, flow [B,H,W,2] f32 -> out [B,C,H,W] f32
// Baseline: one thread per (b,h,w); compute 4 corner weights once, loop C channels,
// 4 predicated global atomicAdd per channel. Output zeroed via hipMemsetAsync.

constexpr int B = 8;
constexpr int C = 16;
constexpr int H = 512;
constexpr int W = 512;
constexpr int HW = H * W;
constexpr int BHW = B * H * W;

__global__ __launch_bounds__(256) void fwarp_scatter(
    const float* __restrict__ im0,
    const float* __restrict__ flow,
    float* __restrict__ out) {

    int idx = blockIdx.x * blockDim.x + threadIdx.x;  // over B*H*W
    if (idx >= BHW) return;

    int w = idx & (W - 1);
    int h = (idx >> 9) & (H - 1);   // W=512 -> shift 9
    int b = idx >> 18;              // H*W = 2^18

    // flow is [B,H,W,2] -> float2 at flat pixel index
    float2 f = reinterpret_cast<const float2*>(flow)[idx];
    float x = (float)w + f.x;
    float y = (float)h + f.y;

    float x0f = floorf(x);
    float y0f = floorf(y);
    int x0 = (int)x0f;
    int y0 = (int)y0f;
    float fx = x - x0f;   // in [0,1)
    float fy = y - y0f;

    float w00 = (1.0f - fx) * (1.0f - fy);  // (x0,y0) NW
    float w01 = fx * (1.0f - fy);           // (x1,y0) NE
    float w10 = (1.0f - fx) * fy;           // (x0,y1) SW
    float w11 = fx * fy;                    // (x1,y1) SE

    bool vx0 = (x0 >= 0) && (x0 < W);
    bool vx1 = (x0 + 1 >= 0) && (x0 + 1 < W);
    bool vy0 = (y0 >= 0) && (y0 < H);
    bool vy1 = (y0 + 1 >= 0) && (y0 + 1 < H);

    bool p00 = vx0 && vy0;
    bool p01 = vx1 && vy0;
    bool p10 = vx0 && vy1;
    bool p11 = vx1 && vy1;
    if (!(p00 | p01 | p10 | p11)) return;

    int i00 = y0 * W + x0;  // may be out of range if invalid; only used when predicate true

    const float* src = im0 + (size_t)b * C * HW + h * W + w;
    float* dst = out + (size_t)b * C * HW;

    #pragma unroll
    for (int c = 0; c < C; ++c) {
        float v = src[(size_t)c * HW];
        float* o = dst + (size_t)c * HW;
        if (p00) atomicAdd(o + i00, v * w00);
        if (p01) atomicAdd(o + i00 + 1, v * w01);
        if (p10) atomicAdd(o + i00 + W, v * w10);
        if (p11) atomicAdd(o + i00 + W + 1, v * w11);
    }
}

extern "C" void kernel_launch(void* const* d_in, const int* in_sizes, int n_in,
                              void* d_out, int out_size, void* d_ws, size_t ws_size,
                              hipStream_t stream) {
    const float* im0  = (const float*)d_in[0];
    const float* flow = (const float*)d_in[1];
    float* out = (float*)d_out;

    // d_out is poisoned 0xAA before every call -> zero it first (capturable).
    hipMemsetAsync(out, 0, (size_t)out_size * sizeof(float), stream);

    int threads = 256;
    int blocks = (BHW + threads - 1) / threads;
    fwarp_scatter<<<blocks, threads, 0, stream>>>(im0, flow, out);
}

// Round 2
// 936.028 us; speedup vs baseline: 5.7295x; 5.7295x over previous
//
#include <hip/hip_runtime.h>

// Forward warp (bilinear splat), gather formulation.
// im0 [B,C,H,W] f32, flow [B,H,W,2] f32 -> out [B,C,H,W] f32.
//
// Each block owns an output tile (TxT spatial, CPB channels) and gathers all
// source pixels within a +/-R halo whose splat corners land in the tile.
// Accumulation in LDS (ds_add_f32), tile written out NON-atomically (each
// output element owned by exactly one block -> no memset, no global atomics).
// Pixels with |flow| > FAR (= R-2) may escape the halo; they are skipped here
// and handled by fwarp_far with global atomics afterwards (P ~ 3.5e-4).

constexpr int B = 8;
constexpr int C = 16;
constexpr int H = 512;
constexpr int W = 512;
constexpr int HW = H * W;

constexpr int T    = 32;          // output tile side
constexpr int R    = 32;          // halo radius
constexpr int HALO = T + 2 * R;   // 96
constexpr int CPB  = 8;           // channels per block
constexpr int CAP  = 3072;        // LDS queue capacity (expected ~1150 entries)
constexpr float FAR = 30.0f;      // = R - 2 safety margin (see proof in session notes)

__global__ __launch_bounds__(256) void fwarp_gather(
    const float* __restrict__ im0,
    const float* __restrict__ flow,
    float* __restrict__ out) {

  __shared__ float acc[CPB * T * T];   // 32 KB
  __shared__ int   queue[CAP];         // 12 KB
  __shared__ int   qcount;

  const int tx0 = blockIdx.x * T;
  const int ty0 = blockIdx.y * T;
  const int b   = blockIdx.z >> 1;
  const int c0  = (blockIdx.z & 1) * CPB;
  const int tid = threadIdx.x;

  for (int i = tid; i < CPB * T * T; i += 256) acc[i] = 0.0f;
  if (tid == 0) qcount = 0;
  __syncthreads();

  const float2* __restrict__ flowv =
      reinterpret_cast<const float2*>(flow) + (size_t)b * HW;
  const float* __restrict__ imb = im0 + ((size_t)b * C + c0) * HW;

  // ---- phase 1: scan halo candidates, compact hits into LDS queue ----
  const int hy0 = ty0 - R, wx0 = tx0 - R;
  for (int i = tid; i < HALO * HALO; i += 256) {
    int cy = i / HALO;
    int cx = i - cy * HALO;
    int hh = hy0 + cy, ww = wx0 + cx;
    if ((unsigned)hh >= (unsigned)H || (unsigned)ww >= (unsigned)W) continue;
    float2 f = flowv[hh * W + ww];
    if (fabsf(f.x) > FAR || fabsf(f.y) > FAR) continue;  // far path handles
    float x = (float)ww + f.x;
    float y = (float)hh + f.y;
    int x0 = (int)floorf(x);
    int y0 = (int)floorf(y);
    // any of the 4 corners inside this tile?
    if (x0 < tx0 - 1 || x0 >= tx0 + T || y0 < ty0 - 1 || y0 >= ty0 + T) continue;
    int slot = atomicAdd(&qcount, 1);
    if (slot < CAP) {
      queue[slot] = hh * W + ww;
    } else {
      // overflow safety net (never expected with random flow): direct global
      // atomics for corners inside this tile, this block's channel range.
      float x0f = floorf(x), y0f = floorf(y);
      float fx = x - x0f, fy = y - y0f;
      float w00 = (1.0f - fx) * (1.0f - fy), w01 = fx * (1.0f - fy);
      float w10 = (1.0f - fx) * fy,          w11 = fx * fy;
      int lx = x0 - tx0, ly = y0 - ty0;
      bool cx0 = (unsigned)lx < (unsigned)T, cx1 = (unsigned)(lx + 1) < (unsigned)T;
      bool cy0 = (unsigned)ly < (unsigned)T, cy1 = (unsigned)(ly + 1) < (unsigned)T;
      float* ob = out + ((size_t)b * C + c0) * HW;
      int g00 = y0 * W + x0;
      for (int c = 0; c < CPB; ++c) {
        float v = imb[(size_t)c * HW + hh * W + ww];
        float* o = ob + (size_t)c * HW;
        if (cx0 & cy0) atomicAdd(o + g00,         v * w00);
        if (cx1 & cy0) atomicAdd(o + g00 + 1,     v * w01);
        if (cx0 & cy1) atomicAdd(o + g00 + W,     v * w10);
        if (cx1 & cy1) atomicAdd(o + g00 + W + 1, v * w11);
      }
    }
  }
  __syncthreads();

  // ---- phase 2: dense processing of queue entries ----
  int n = min(qcount, CAP);
  for (int e = tid; e < n; e += 256) {
    int p = queue[e];
    int hh = p >> 9, ww = p & (W - 1);   // W = 512
    float2 f = flowv[p];                 // L2-hot reload
    float x = (float)ww + f.x;
    float y = (float)hh + f.y;
    float x0f = floorf(x), y0f = floorf(y);
    float fx = x - x0f, fy = y - y0f;
    float w00 = (1.0f - fx) * (1.0f - fy), w01 = fx * (1.0f - fy);
    float w10 = (1.0f - fx) * fy,          w11 = fx * fy;
    int lx = (int)x0f - tx0, ly = (int)y0f - ty0;
    bool cx0 = (unsigned)lx < (unsigned)T, cx1 = (unsigned)(lx + 1) < (unsigned)T;
    bool cy0 = (unsigned)ly < (unsigned)T, cy1 = (unsigned)(ly + 1) < (unsigned)T;
    int base = ly * T + lx;  // corners inside tile are individually predicated
    const float* sp = imb + hh * W + ww;
    #pragma unroll
    for (int c = 0; c < CPB; ++c) {
      float v = sp[(size_t)c * HW];
      float* a = acc + c * T * T;
      if (cx0 & cy0) atomicAdd(a + base,         v * w00);
      if (cx1 & cy0) atomicAdd(a + base + 1,     v * w01);
      if (cx0 & cy1) atomicAdd(a + base + T,     v * w10);
      if (cx1 & cy1) atomicAdd(a + base + T + 1, v * w11);
    }
  }
  __syncthreads();

  // ---- phase 3: non-atomic coalesced tile writeout ----
  float* ob = out + ((size_t)b * C + c0) * HW + ty0 * W + tx0;
  for (int k = tid; k < CPB * T * T; k += 256) {
    int c = k >> 10;            // T*T = 1024
    int r = (k >> 5) & (T - 1);
    int x = k & (T - 1);
    ob[(size_t)c * HW + r * W + x] = acc[k];
  }
}

// Rare path: pixels whose flow exceeds FAR in either component.
__global__ __launch_bounds__(256) void fwarp_far(
    const float* __restrict__ im0,
    const float* __restrict__ flow,
    float* __restrict__ out) {

  int idx = blockIdx.x * blockDim.x + threadIdx.x;  // over B*H*W
  if (idx >= B * HW) return;
  float2 f = reinterpret_cast<const float2*>(flow)[idx];
  if (!(fabsf(f.x) > FAR || fabsf(f.y) > FAR)) return;

  int w = idx & (W - 1);
  int h = (idx >> 9) & (H - 1);
  int b = idx >> 18;

  float x = (float)w + f.x;
  float y = (float)h + f.y;
  float x0f = floorf(x), y0f = floorf(y);
  int x0 = (int)x0f, y0 = (int)y0f;
  float fx = x - x0f, fy = y - y0f;
  float w00 = (1.0f - fx) * (1.0f - fy), w01 = fx * (1.0f - fy);
  float w10 = (1.0f - fx) * fy,          w11 = fx * fy;

  bool vx0 = (unsigned)x0 < (unsigned)W;
  bool vx1 = (unsigned)(x0 + 1) < (unsigned)W;
  bool vy0 = (unsigned)y0 < (unsigned)H;
  bool vy1 = (unsigned)(y0 + 1) < (unsigned)H;
  bool p00 = vx0 && vy0, p01 = vx1 && vy0, p10 = vx0 && vy1, p11 = vx1 && vy1;
  if (!(p00 | p01 | p10 | p11)) return;

  int g00 = y0 * W + x0;
  const float* src = im0 + (size_t)b * C * HW + h * W + w;
  float* dst = out + (size_t)b * C * HW;
  for (int c = 0; c < C; ++c) {
    float v = src[(size_t)c * HW];
    float* o = dst + (size_t)c * HW;
    if (p00) atomicAdd(o + g00,         v * w00);
    if (p01) atomicAdd(o + g00 + 1,     v * w01);
    if (p10) atomicAdd(o + g00 + W,     v * w10);
    if (p11) atomicAdd(o + g00 + W + 1, v * w11);
  }
}

extern "C" void kernel_launch(void* const* d_in, const int* in_sizes, int n_in,
                              void* d_out, int out_size, void* d_ws, size_t ws_size,
                              hipStream_t stream) {
  const float* im0  = (const float*)d_in[0];
  const float* flow = (const float*)d_in[1];
  float* out = (float*)d_out;

  // Gather kernel writes every output element with "=" -> no memset needed.
  dim3 grid(W / T, H / T, B * (C / CPB));  // 16 x 16 x 16
  fwarp_gather<<<grid, 256, 0, stream>>>(im0, flow, out);

  // Rare far-flow pixels splat on top with global atomics (runs after).
  int blocks = (B * HW + 255) / 256;
  fwarp_far<<<blocks, 256, 0, stream>>>(im0, flow, out);
}

// Round 3
// 904.622 us; speedup vs baseline: 5.9284x; 1.0347x over previous
//
#include <hip/hip_runtime.h>

// Forward warp (bilinear splat), gather formulation, v2.
// im0 [B,C,H,W] f32, flow [B,H,W,2] f32 -> out [B,C,H,W] f32.
//
// Each block owns a 16x16 output tile x ALL 16 channels. Scans the +/-32 halo
// for source pixels whose splat corners land in the tile, compacts them into
// an LDS queue, then processes (entry x channel-group) work items with LDS
// atomic accumulation. Tile written out non-atomically (exclusive ownership).
// LDS ~19.7 KB -> 8 blocks/CU (100% occupancy target; R1 was 32%).
// Pixels with |flow| > 30 handled by fwarp_far afterwards (P ~ 3.5e-4).

constexpr int B = 8;
constexpr int C = 16;
constexpr int H = 512;
constexpr int W = 512;
constexpr int HW = H * W;

constexpr int T    = 16;          // output tile side
constexpr int R    = 32;          // halo radius (covers |flow| <= 30)
constexpr int HALO = T + 2 * R;   // 80
constexpr int CAP  = 768;         // queue capacity (expected ~300 entries)
constexpr int ASTR = 260;         // acc channel stride: 16B-aligned, cg banks {0,16} (2-way = free)
constexpr float FARTH = 30.0f;

__global__ __launch_bounds__(256, 7) void fwarp_gather(
    const float* __restrict__ im0,
    const float* __restrict__ flow,
    float* __restrict__ out) {

  __shared__ float acc[C * ASTR];   // 16*260*4 = 16640 B
  __shared__ int   queue[CAP];      // 3072 B
  __shared__ int   qcount;

  const int tx0 = blockIdx.x * T;
  const int ty0 = blockIdx.y * T;
  const int b   = blockIdx.z;
  const int tid = threadIdx.x;

  for (int i = tid; i < C * ASTR; i += 256) acc[i] = 0.0f;
  if (tid == 0) qcount = 0;
  __syncthreads();

  const float2* __restrict__ flowv =
      reinterpret_cast<const float2*>(flow) + (size_t)b * HW;
  const float* __restrict__ imb = im0 + (size_t)b * C * HW;

  // ---- phase 1: scan halo, compact hits into LDS queue ----
  const int hy0 = ty0 - R, wx0 = tx0 - R;
  for (int i = tid; i < HALO * HALO; i += 256) {
    int cy = i / HALO;
    int cx = i - cy * HALO;
    int hh = hy0 + cy, ww = wx0 + cx;
    if ((unsigned)hh >= (unsigned)H || (unsigned)ww >= (unsigned)W) continue;
    int p = hh * W + ww;
    float2 f = flowv[p];
    if (fabsf(f.x) > FARTH || fabsf(f.y) > FARTH) continue;  // far kernel handles
    float x = (float)ww + f.x;
    float y = (float)hh + f.y;
    int x0 = (int)floorf(x);
    int y0 = (int)floorf(y);
    // claim iff any of the 4 corners lies in this tile:
    if (x0 < tx0 - 1 || x0 > tx0 + T - 1 || y0 < ty0 - 1 || y0 > ty0 + T - 1)
      continue;
    int slot = atomicAdd(&qcount, 1);
    if (slot < CAP) {
      queue[slot] = p;
    } else {
      // overflow (never expected): accumulate into LDS acc inline (no race
      // with phase-3 store, unlike a global-atomic fallback would have).
      float x0f = floorf(x), y0f = floorf(y);
      float fx = x - x0f, fy = y - y0f;
      float w00 = (1.0f - fx) * (1.0f - fy), w01 = fx * (1.0f - fy);
      float w10 = (1.0f - fx) * fy,          w11 = fx * fy;
      int lx = x0 - tx0, ly = y0 - ty0;
      bool cx0 = (unsigned)lx < (unsigned)T, cx1 = (unsigned)(lx + 1) < (unsigned)T;
      bool cy0 = (unsigned)ly < (unsigned)T, cy1 = (unsigned)(ly + 1) < (unsigned)T;
      int base = ly * T + lx;
      for (int c = 0; c < C; ++c) {
        float v = imb[(size_t)c * HW + p];
        float* a = acc + c * ASTR;
        if (cx0 & cy0) atomicAdd(a + base,         v * w00);
        if (cx1 & cy0) atomicAdd(a + base + 1,     v * w01);
        if (cx0 & cy1) atomicAdd(a + base + T,     v * w10);
        if (cx1 & cy1) atomicAdd(a + base + T + 1, v * w11);
      }
    }
  }
  __syncthreads();

  // ---- phase 2: (entry x channel-group) work items; 4 threads per entry ----
  int n = min(qcount, CAP);
  for (int k = tid; k < n * 4; k += 256) {
    int e  = k >> 2;
    int cg = (k & 3) * 4;        // channel group: 0,4,8,12
    int p  = queue[e];
    int hh = p >> 9, ww = p & (W - 1);
    float2 f = flowv[p];         // L2-hot; 4 lanes same address -> broadcast
    float x = (float)ww + f.x;
    float y = (float)hh + f.y;
    float x0f = floorf(x), y0f = floorf(y);
    float fx = x - x0f, fy = y - y0f;
    float w00 = (1.0f - fx) * (1.0f - fy), w01 = fx * (1.0f - fy);
    float w10 = (1.0f - fx) * fy,          w11 = fx * fy;
    int lx = (int)x0f - tx0, ly = (int)y0f - ty0;
    bool cx0 = (unsigned)lx < (unsigned)T, cx1 = (unsigned)(lx + 1) < (unsigned)T;
    bool cy0 = (unsigned)ly < (unsigned)T, cy1 = (unsigned)(ly + 1) < (unsigned)T;
    int base = ly * T + lx;
    const float* sp = imb + (size_t)cg * HW + p;
    float* a = acc + cg * ASTR;
    #pragma unroll
    for (int c = 0; c < 4; ++c) {
      float v = sp[(size_t)c * HW];
      float* ac = a + c * ASTR;
      if (cx0 & cy0) atomicAdd(ac + base,         v * w00);
      if (cx1 & cy0) atomicAdd(ac + base + 1,     v * w01);
      if (cx0 & cy1) atomicAdd(ac + base + T,     v * w10);
      if (cx1 & cy1) atomicAdd(ac + base + T + 1, v * w11);
    }
  }
  __syncthreads();

  // ---- phase 3: non-atomic float4 tile writeout ----
  float* ob = out + (size_t)b * C * HW + ty0 * W + tx0;
  for (int k = tid; k < C * T * T / 4; k += 256) {   // 1024 float4 stores
    int c   = k >> 6;
    int idx = k & 63;
    int r   = idx >> 2;
    int x4  = (idx & 3) * 4;
    const float* s = acc + c * ASTR + r * T + x4;
    float4 v = make_float4(s[0], s[1], s[2], s[3]);
    *reinterpret_cast<float4*>(ob + (size_t)c * HW + r * W + x4) = v;
  }
}

// Rare path: pixels whose flow exceeds FARTH in either component.
__global__ __launch_bounds__(256) void fwarp_far(
    const float* __restrict__ im0,
    const float* __restrict__ flow,
    float* __restrict__ out) {

  int idx = blockIdx.x * blockDim.x + threadIdx.x;  // over B*H*W
  if (idx >= B * HW) return;
  float2 f = reinterpret_cast<const float2*>(flow)[idx];
  if (!(fabsf(f.x) > FARTH || fabsf(f.y) > FARTH)) return;

  int w = idx & (W - 1);
  int h = (idx >> 9) & (H - 1);
  int b = idx >> 18;

  float x = (float)w + f.x;
  float y = (float)h + f.y;
  float x0f = floorf(x), y0f = floorf(y);
  int x0 = (int)x0f, y0 = (int)y0f;
  float fx = x - x0f, fy = y - y0f;
  float w00 = (1.0f - fx) * (1.0f - fy), w01 = fx * (1.0f - fy);
  float w10 = (1.0f - fx) * fy,          w11 = fx * fy;

  bool vx0 = (unsigned)x0 < (unsigned)W;
  bool vx1 = (unsigned)(x0 + 1) < (unsigned)W;
  bool vy0 = (unsigned)y0 < (unsigned)H;
  bool vy1 = (unsigned)(y0 + 1) < (unsigned)H;
  bool p00 = vx0 && vy0, p01 = vx1 && vy0, p10 = vx0 && vy1, p11 = vx1 && vy1;
  if (!(p00 | p01 | p10 | p11)) return;

  int g00 = y0 * W + x0;
  const float* src = im0 + (size_t)b * C * HW + h * W + w;
  float* dst = out + (size_t)b * C * HW;
  for (int c = 0; c < C; ++c) {
    float v = src[(size_t)c * HW];
    float* o = dst + (size_t)c * HW;
    if (p00) atomicAdd(o + g00,         v * w00);
    if (p01) atomicAdd(o + g00 + 1,     v * w01);
    if (p10) atomicAdd(o + g00 + W,     v * w10);
    if (p11) atomicAdd(o + g00 + W + 1, v * w11);
  }
}

extern "C" void kernel_launch(void* const* d_in, const int* in_sizes, int n_in,
                              void* d_out, int out_size, void* d_ws, size_t ws_size,
                              hipStream_t stream) {
  const float* im0  = (const float*)d_in[0];
  const float* flow = (const float*)d_in[1];
  float* out = (float*)d_out;

  // Gather kernel writes every output element with "=" -> no memset needed.
  dim3 grid(W / T, H / T, B);   // 32 x 32 x 8 = 8192 blocks
  fwarp_gather<<<grid, 256, 0, stream>>>(im0, flow, out);

  // Rare far-flow pixels splat on top with global atomics (runs after).
  int blocks = (B * HW + 255) / 256;
  fwarp_far<<<blocks, 256, 0, stream>>>(im0, flow, out);
}